// Round 1
// baseline (1043.478 us; speedup 1.0000x reference)
//
#include <hip/hip_runtime.h>
#include <stdint.h>

#define N 8192
#define NCLS 80
#define NW 128            // N/64 bitmask words per row

// ---------------- K1: per-box prep -------------------------------------
__global__ void k_prep(const float* __restrict__ box,
                       const float* __restrict__ conf,
                       const float* __restrict__ logits,
                       unsigned long long* __restrict__ key,
                       int* __restrict__ cls,
                       int* __restrict__ Vcnt) {
    int i = blockIdx.x * blockDim.x + threadIdx.x;
    if (i >= N) return;
    float c = conf[i];
    bool valid = c > 0.5f;

    // argmax over 80 logits, first-max wins (matches jnp.argmax)
    const float4* lp = (const float4*)(logits + (size_t)i * NCLS);
    float best = -INFINITY;
    int bi = 0;
#pragma unroll 4
    for (int j4 = 0; j4 < NCLS / 4; ++j4) {
        float4 v = lp[j4];
        if (v.x > best) { best = v.x; bi = j4 * 4 + 0; }
        if (v.y > best) { best = v.y; bi = j4 * 4 + 1; }
        if (v.z > best) { best = v.z; bi = j4 * 4 + 2; }
        if (v.w > best) { best = v.w; bi = j4 * 4 + 3; }
    }
    cls[i] = bi;

    unsigned int kb;
    if (valid) {
        kb = ~__float_as_uint(c);   // ascending kb == descending conf (conf>0)
        atomicAdd(Vcnt, 1);
    } else {
        kb = 0xFFFFFFFFu;           // all invalid sort last, tie-broken by idx
    }
    key[i] = ((unsigned long long)kb << 32) | (unsigned int)i;
}

// ---------------- K2: counting rank (stable argsort) --------------------
__global__ void k_rank(const unsigned long long* __restrict__ key,
                       int* __restrict__ order,
                       int* __restrict__ rankArr) {
    __shared__ unsigned long long tile[2048];
    int i = blockIdx.x * blockDim.x + threadIdx.x;   // 8192 threads total
    unsigned long long my = key[i];
    int r = 0;
    for (int t0 = 0; t0 < N; t0 += 2048) {
        __syncthreads();
        for (int j = threadIdx.x; j < 2048; j += 256) tile[j] = key[t0 + j];
        __syncthreads();
#pragma unroll 8
        for (int j = 0; j < 2048; ++j) r += (tile[j] < my) ? 1 : 0;
    }
    rankArr[i] = r;
    order[r] = i;   // keys are distinct (idx in low bits) -> permutation
}

// ---------------- K3: gather into sorted order --------------------------
__global__ void k_gather(const int* __restrict__ order,
                         const float* __restrict__ box,
                         const int* __restrict__ cls,
                         float* __restrict__ sx1, float* __restrict__ sy1,
                         float* __restrict__ sx2, float* __restrict__ sy2,
                         float* __restrict__ sarea, int* __restrict__ scls) {
#pragma clang fp contract(off)
    int r = blockIdx.x * blockDim.x + threadIdx.x;
    if (r >= N) return;
    int i = order[r];
    float x = box[i * 4 + 0], y = box[i * 4 + 1];
    float w = box[i * 4 + 2], h = box[i * 4 + 3];
    float hw = w * 0.5f, hh = h * 0.5f;   // == w/2 exactly
    sx1[r] = x - hw;
    sy1[r] = y - hh;
    sx2[r] = x + hw;
    sy2[r] = y + hh;
    sarea[r] = w * h;
    scls[r] = cls[i];
}

// ---------------- K4: suppression bitmask matrix (sorted space) ---------
// thread (r, wc): 64 IoUs of row r vs columns [wc*64, wc*64+63], bits c>r.
__global__ void k_matrix(const float* __restrict__ sx1, const float* __restrict__ sy1,
                         const float* __restrict__ sx2, const float* __restrict__ sy2,
                         const float* __restrict__ sarea, const int* __restrict__ scls,
                         const int* __restrict__ Vcnt,
                         unsigned long long* __restrict__ mat) {
#pragma clang fp contract(off)
    int V = *Vcnt;
    int r = blockIdx.x * 2 + threadIdx.y;
    int wc = threadIdx.x;
    if (r >= V) return;            // rows >= V never read by scan
    if (wc < (r >> 6)) return;     // words strictly before row's chunk never read

    float rx1 = sx1[r], ry1 = sy1[r], rx2 = sx2[r], ry2 = sy2[r], rar = sarea[r];
    int rcls = scls[r];
    int cbase = wc * 64;
    unsigned long long bits = 0ULL;
    for (int k = 0; k < 64; ++k) {
        int c = cbase + k;
        if (c <= r) continue;      // strict "later"
        // exact float32 op order of the reference:
        float iw = fminf(rx2, sx2[c]) - fmaxf(rx1, sx1[c]);
        iw = fmaxf(iw, 0.0f);
        float ih = fminf(ry2, sy2[c]) - fmaxf(ry1, sy1[c]);
        ih = fmaxf(ih, 0.0f);
        float inter = iw * ih;
        float uni = (rar + sarea[c]) - inter;
        float iou = __fdiv_rn(inter, uni);       // IEEE-rounded divide
        bool sup = (iou > 0.5f) && (scls[c] == rcls);
        bits |= ((unsigned long long)sup) << k;
    }
    mat[(size_t)r * NW + wc] = bits;
}

// ---------------- K5: sequential greedy scan, 64-rank chunks ------------
__global__ void __launch_bounds__(1024) k_scan(const unsigned long long* __restrict__ mat,
                                               const int* __restrict__ Vcnt,
                                               unsigned long long* __restrict__ keepw) {
    __shared__ unsigned long long supp[NW];
    __shared__ unsigned long long mrow[64];
    __shared__ unsigned long long part[8][NW];
    __shared__ unsigned long long kws;
    int tid = threadIdx.x;
    int V = *Vcnt;
    int nc = (V + 63) >> 6;

    if (tid < NW) { supp[tid] = 0ULL; keepw[tid] = 0ULL; }
    __syncthreads();

    for (int c = 0; c < nc; ++c) {
        // stage this chunk's diagonal words (intra-chunk suppression rows)
        if (tid < 64) {
            int r = c * 64 + tid;
            mrow[tid] = (r < V) ? mat[(size_t)r * NW + c] : 0ULL;
        }
        __syncthreads();
        // 64-step sequential greedy scan on one lane, in registers
        if (tid == 0) {
            unsigned long long s = supp[c];
            unsigned long long kw = 0ULL;
            int lim = V - c * 64; if (lim > 64) lim = 64;
            for (int k = 0; k < lim; ++k) {
                if (!((s >> k) & 1ULL)) {
                    kw |= 1ULL << k;
                    s |= mrow[k];          // mrow[k] only has bits > k
                }
            }
            kws = kw;
            keepw[c] = kw;
        }
        __syncthreads();
        unsigned long long kw = kws;       // uniform
        if (kw) {
            int g = tid >> 7;              // 0..7 row-groups
            int w = tid & 127;             // word index
            unsigned long long acc = 0ULL;
            if (w > c) {                   // only future words matter
                for (int k = g; k < 64; k += 8) {
                    if ((kw >> k) & 1ULL) {
                        acc |= mat[(size_t)(c * 64 + k) * NW + w];
                    }
                }
            }
            part[g][w] = acc;
            __syncthreads();
            if (tid < NW) {
                unsigned long long s = supp[tid];
#pragma unroll
                for (int g2 = 0; g2 < 8; ++g2) s |= part[g2][tid];
                supp[tid] = s;
            }
        }
        __syncthreads();
    }
}

// ---------------- K6: outputs -------------------------------------------
__global__ void k_out(const float* __restrict__ box,
                      const float* __restrict__ conf,
                      const int* __restrict__ cls,
                      const int* __restrict__ rankArr,
                      const unsigned long long* __restrict__ keepw,
                      float* __restrict__ out) {
    int i = blockIdx.x * blockDim.x + threadIdx.x;
    if (i >= N) return;
    int r = rankArr[i];
    float m = (float)((keepw[r >> 6] >> (r & 63)) & 1ULL);
    float4 b = ((const float4*)box)[i];
    out[i * 5 + 0] = b.x * m;
    out[i * 5 + 1] = b.y * m;
    out[i * 5 + 2] = b.z * m;
    out[i * 5 + 3] = b.w * m;
    out[i * 5 + 4] = conf[i] * m;
    out[5 * N + i] = (float)cls[i];
    out[6 * N + i] = m;
}

// ---------------- launch -------------------------------------------------
extern "C" void kernel_launch(void* const* d_in, const int* in_sizes, int n_in,
                              void* d_out, int out_size, void* d_ws, size_t ws_size,
                              hipStream_t stream) {
    const float* box    = (const float*)d_in[0];
    const float* conf   = (const float*)d_in[1];
    const float* logits = (const float*)d_in[2];
    float* out = (float*)d_out;

    char* ws = (char*)d_ws;
    unsigned long long* key  = (unsigned long long*)(ws + 0);        // 64 KB
    int*   cls     = (int*)  (ws + 65536);                           // 32 KB
    int*   order   = (int*)  (ws + 98304);                           // 32 KB
    int*   rankArr = (int*)  (ws + 131072);                          // 32 KB
    float* sx1     = (float*)(ws + 163840);
    float* sy1     = (float*)(ws + 196608);
    float* sx2     = (float*)(ws + 229376);
    float* sy2     = (float*)(ws + 262144);
    float* sarea   = (float*)(ws + 294912);
    int*   scls    = (int*)  (ws + 327680);
    int*   Vcnt    = (int*)  (ws + 360448);
    unsigned long long* keepw = (unsigned long long*)(ws + 360512);  // 1 KB
    unsigned long long* mat   = (unsigned long long*)(ws + 393216);  // 8 MB

    hipMemsetAsync(Vcnt, 0, sizeof(int), stream);

    k_prep<<<N / 256, 256, 0, stream>>>(box, conf, logits, key, cls, Vcnt);
    k_rank<<<N / 256, 256, 0, stream>>>(key, order, rankArr);
    k_gather<<<N / 256, 256, 0, stream>>>(order, box, cls, sx1, sy1, sx2, sy2, sarea, scls);
    k_matrix<<<N / 2, dim3(128, 2), 0, stream>>>(sx1, sy1, sx2, sy2, sarea, scls, Vcnt, mat);
    k_scan<<<1, 1024, 0, stream>>>(mat, Vcnt, keepw);
    k_out<<<N / 256, 256, 0, stream>>>(box, conf, cls, rankArr, keepw, out);
}

// Round 2
// 463.677 us; speedup vs baseline: 2.2504x; 2.2504x over previous
//
#include <hip/hip_runtime.h>
#include <stdint.h>

#define N 8192
#define NCLS 80
#define NW 128            // N/64 bitmask words per row

// ---------------- K1: per-box prep -------------------------------------
__global__ void k_prep(const float* __restrict__ box,
                       const float* __restrict__ conf,
                       const float* __restrict__ logits,
                       unsigned long long* __restrict__ key,
                       int* __restrict__ cls,
                       int* __restrict__ Vcnt) {
    int i = blockIdx.x * blockDim.x + threadIdx.x;
    if (i >= N) return;
    float c = conf[i];
    bool valid = c > 0.5f;

    // argmax over 80 logits, first-max wins (matches jnp.argmax)
    const float4* lp = (const float4*)(logits + (size_t)i * NCLS);
    float best = -INFINITY;
    int bi = 0;
#pragma unroll 4
    for (int j4 = 0; j4 < NCLS / 4; ++j4) {
        float4 v = lp[j4];
        if (v.x > best) { best = v.x; bi = j4 * 4 + 0; }
        if (v.y > best) { best = v.y; bi = j4 * 4 + 1; }
        if (v.z > best) { best = v.z; bi = j4 * 4 + 2; }
        if (v.w > best) { best = v.w; bi = j4 * 4 + 3; }
    }
    cls[i] = bi;

    unsigned int kb;
    if (valid) {
        kb = ~__float_as_uint(c);   // ascending kb == descending conf (conf>0)
        atomicAdd(Vcnt, 1);
    } else {
        kb = 0xFFFFFFFFu;           // all invalid sort last, tie-broken by idx
    }
    key[i] = ((unsigned long long)kb << 32) | (unsigned int)i;
}

// ---------------- K2: counting rank (stable argsort), 8-way j-split -----
__global__ __launch_bounds__(256) void k_rank(const unsigned long long* __restrict__ key,
                                              int* __restrict__ rankArr) {
    __shared__ unsigned long long tile[1024];
    int i = blockIdx.x * 256 + threadIdx.x;
    unsigned long long my = key[i];
    int j0 = blockIdx.y * 1024;
    for (int j = threadIdx.x; j < 1024; j += 256) tile[j] = key[j0 + j];
    __syncthreads();
    int rr = 0;
#pragma unroll 16
    for (int j = 0; j < 1024; ++j) rr += (tile[j] < my) ? 1 : 0;
    if (rr) atomicAdd(&rankArr[i], rr);
}

__global__ void k_scatter(const int* __restrict__ rankArr, int* __restrict__ order) {
    int i = blockIdx.x * blockDim.x + threadIdx.x;
    if (i >= N) return;
    order[rankArr[i]] = i;   // keys distinct (idx in low bits) -> permutation
}

// ---------------- K3: gather into sorted order --------------------------
__global__ void k_gather(const int* __restrict__ order,
                         const float* __restrict__ box,
                         const int* __restrict__ cls,
                         float4* __restrict__ sbx,
                         float* __restrict__ sarea, int* __restrict__ scls) {
#pragma clang fp contract(off)
    int r = blockIdx.x * blockDim.x + threadIdx.x;
    if (r >= N) return;
    int i = order[r];
    float4 b = ((const float4*)box)[i];          // x, y, w, h
    float hw = b.z * 0.5f, hh = b.w * 0.5f;      // == w/2 exactly
    sbx[r] = make_float4(b.x - hw, b.y - hh, b.x + hw, b.y + hh);
    sarea[r] = b.z * b.w;
    scls[r] = cls[i];
}

// ---------------- K4: suppression bitmask matrix (sorted space) ---------
// block (rowblk=blockIdx.x, colblk=blockIdx.y): 256 rows x 256 cols tile.
// Column data staged in LDS; all lane reads are same-address broadcasts.
__global__ __launch_bounds__(256) void k_matrix(const float4* __restrict__ sbx,
                                                const float* __restrict__ sarea,
                                                const int* __restrict__ scls,
                                                const int* __restrict__ Vcnt,
                                                unsigned long long* __restrict__ mat) {
#pragma clang fp contract(off)
    __shared__ float4 cb[256];
    __shared__ float  ca[256];
    __shared__ int    cc[256];
    int rbase = blockIdx.x * 256;
    int cbase = blockIdx.y * 256;
    if (cbase < rbase) return;               // strictly sub-diagonal: never read
    int V = *Vcnt;
    if (rbase >= V) return;                  // rows >= V never read by scan

    int r = rbase + threadIdx.x;
    bool active = (r < V);
    float4 rb4; float rar; int rcls;
    if (active) { rb4 = sbx[r]; rar = sarea[r]; rcls = scls[r]; }

    int t = cbase + threadIdx.x;
    cb[threadIdx.x] = sbx[t];
    ca[threadIdx.x] = sarea[t];
    cc[threadIdx.x] = scls[t];
    __syncthreads();
    if (!active) return;

    int rw = r >> 6;
#pragma unroll
    for (int w = 0; w < 4; ++w) {
        int wc = (cbase >> 6) + w;
        if (wc < rw) continue;               // words before row's chunk: never read
        unsigned long long bits = 0ULL;
        int k0 = w * 64;
#pragma unroll 4
        for (int k = 0; k < 64; ++k) {
            int c = cbase + k0 + k;
            float4 c4 = cb[k0 + k];
            // exact float32 op order of the reference:
            float iw = fminf(rb4.z, c4.z) - fmaxf(rb4.x, c4.x);
            iw = fmaxf(iw, 0.0f);
            float ih = fminf(rb4.w, c4.w) - fmaxf(rb4.y, c4.y);
            ih = fmaxf(ih, 0.0f);
            float inter = iw * ih;
            float uni = rar + ca[k0 + k] - inter;
            float iou = __fdiv_rn(inter, uni);       // IEEE-rounded divide
            bool sup = (iou > 0.5f) & (cc[k0 + k] == rcls) & (c > r);
            bits |= ((unsigned long long)sup) << k;
        }
        mat[(size_t)r * NW + wc] = bits;
    }
}

// ---------------- K5: sequential greedy scan, lazy supp gather ----------
// Per 64-rank chunk c: waves 0-14 OR-gather supp word c over kept earlier
// rows (parallel global round-trip) while wave 15 loads the diagonal words;
// then lane 0 does the 64-step register scan.
__global__ void __launch_bounds__(1024) k_scan(const unsigned long long* __restrict__ mat,
                                               const int* __restrict__ Vcnt,
                                               unsigned long long* __restrict__ keepw) {
    __shared__ unsigned long long mrow[64];
    __shared__ unsigned long long keep_s[NW];
    __shared__ unsigned long long red[16];
    int tid = threadIdx.x;
    int wv = tid >> 6, lane = tid & 63;
    int V = *Vcnt;
    int nc = (V + 63) >> 6;

    if (tid < NW) keep_s[tid] = 0ULL;
    if (tid < 16) red[tid] = 0ULL;
    __syncthreads();

    for (int c = 0; c < nc; ++c) {
        if (wv == 15) {
            int r = c * 64 + lane;
            mrow[lane] = (r < V) ? mat[(size_t)r * NW + c] : 0ULL;
        } else {
            unsigned long long part = 0ULL;
            for (int r = tid; r < c * 64; r += 960) {
                if ((keep_s[r >> 6] >> (r & 63)) & 1ULL)
                    part |= mat[(size_t)r * NW + c];
            }
#pragma unroll
            for (int off = 32; off > 0; off >>= 1)
                part |= __shfl_down(part, off);
            if (lane == 0) red[wv] = part;
        }
        __syncthreads();
        if (tid == 0) {
            unsigned long long s = 0ULL;
#pragma unroll
            for (int w = 0; w < 15; ++w) s |= red[w];
            unsigned long long kw = 0ULL;
            int lim = V - c * 64; if (lim > 64) lim = 64;
            for (int k = 0; k < lim; ++k) {
                if (!((s >> k) & 1ULL)) {
                    kw |= 1ULL << k;
                    s |= mrow[k];          // mrow[k] only has bits > k
                }
            }
            keep_s[c] = kw;
            keepw[c] = kw;
        }
        __syncthreads();
    }
    if (tid < NW && tid >= nc) keepw[tid] = 0ULL;
}

// ---------------- K6: outputs -------------------------------------------
__global__ void k_out(const float* __restrict__ box,
                      const float* __restrict__ conf,
                      const int* __restrict__ cls,
                      const int* __restrict__ rankArr,
                      const unsigned long long* __restrict__ keepw,
                      float* __restrict__ out) {
    int i = blockIdx.x * blockDim.x + threadIdx.x;
    if (i >= N) return;
    int r = rankArr[i];
    float m = (float)((keepw[r >> 6] >> (r & 63)) & 1ULL);
    float4 b = ((const float4*)box)[i];
    out[i * 5 + 0] = b.x * m;
    out[i * 5 + 1] = b.y * m;
    out[i * 5 + 2] = b.z * m;
    out[i * 5 + 3] = b.w * m;
    out[i * 5 + 4] = conf[i] * m;
    out[5 * N + i] = (float)cls[i];
    out[6 * N + i] = m;
}

// ---------------- launch -------------------------------------------------
extern "C" void kernel_launch(void* const* d_in, const int* in_sizes, int n_in,
                              void* d_out, int out_size, void* d_ws, size_t ws_size,
                              hipStream_t stream) {
    const float* box    = (const float*)d_in[0];
    const float* conf   = (const float*)d_in[1];
    const float* logits = (const float*)d_in[2];
    float* out = (float*)d_out;

    char* ws = (char*)d_ws;
    unsigned long long* key  = (unsigned long long*)(ws + 0);        // 64 KB
    int*    cls     = (int*)   (ws + 65536);                         // 32 KB
    int*    order   = (int*)   (ws + 98304);                         // 32 KB
    int*    rankArr = (int*)   (ws + 131072);                        // 32 KB
    float4* sbx     = (float4*)(ws + 163840);                        // 128 KB
    float*  sarea   = (float*) (ws + 294912);                        // 32 KB
    int*    scls    = (int*)   (ws + 327680);                        // 32 KB
    int*    Vcnt    = (int*)   (ws + 360448);
    unsigned long long* keepw = (unsigned long long*)(ws + 360512);  // 1 KB
    unsigned long long* mat   = (unsigned long long*)(ws + 393216);  // 8 MB

    hipMemsetAsync(Vcnt, 0, sizeof(int), stream);
    hipMemsetAsync(rankArr, 0, N * sizeof(int), stream);

    k_prep<<<N / 256, 256, 0, stream>>>(box, conf, logits, key, cls, Vcnt);
    k_rank<<<dim3(N / 256, 8), 256, 0, stream>>>(key, rankArr);
    k_scatter<<<N / 256, 256, 0, stream>>>(rankArr, order);
    k_gather<<<N / 256, 256, 0, stream>>>(order, box, cls, sbx, sarea, scls);
    k_matrix<<<dim3(N / 256, N / 256), 256, 0, stream>>>(sbx, sarea, scls, Vcnt, mat);
    k_scan<<<1, 1024, 0, stream>>>(mat, Vcnt, keepw);
    k_out<<<N / 256, 256, 0, stream>>>(box, conf, cls, rankArr, keepw, out);
}

// Round 3
// 215.124 us; speedup vs baseline: 4.8506x; 2.1554x over previous
//
#include <hip/hip_runtime.h>
#include <stdint.h>

#define N 8192
#define NCLS 80
#define NW 128            // N/64 bitmask words per row

// ---------------- K1: per-box prep -------------------------------------
__global__ void k_prep(const float* __restrict__ box,
                       const float* __restrict__ conf,
                       const float* __restrict__ logits,
                       unsigned long long* __restrict__ key,
                       int* __restrict__ cls,
                       int* __restrict__ Vcnt) {
    int i = blockIdx.x * blockDim.x + threadIdx.x;
    if (i >= N) return;
    float c = conf[i];
    bool valid = c > 0.5f;

    // argmax over 80 logits, first-max wins (matches jnp.argmax)
    const float4* lp = (const float4*)(logits + (size_t)i * NCLS);
    float best = -INFINITY;
    int bi = 0;
#pragma unroll 4
    for (int j4 = 0; j4 < NCLS / 4; ++j4) {
        float4 v = lp[j4];
        if (v.x > best) { best = v.x; bi = j4 * 4 + 0; }
        if (v.y > best) { best = v.y; bi = j4 * 4 + 1; }
        if (v.z > best) { best = v.z; bi = j4 * 4 + 2; }
        if (v.w > best) { best = v.w; bi = j4 * 4 + 3; }
    }
    cls[i] = bi;

    unsigned int kb;
    if (valid) {
        kb = ~__float_as_uint(c);   // ascending kb == descending conf (conf>0)
        atomicAdd(Vcnt, 1);
    } else {
        kb = 0xFFFFFFFFu;           // all invalid sort last, tie-broken by idx
    }
    key[i] = ((unsigned long long)kb << 32) | (unsigned int)i;
}

// ---------------- K2: counting rank (stable argsort), 8-way j-split -----
__global__ __launch_bounds__(256) void k_rank(const unsigned long long* __restrict__ key,
                                              int* __restrict__ rankArr) {
    __shared__ unsigned long long tile[1024];
    int i = blockIdx.x * 256 + threadIdx.x;
    unsigned long long my = key[i];
    int j0 = blockIdx.y * 1024;
    for (int j = threadIdx.x; j < 1024; j += 256) tile[j] = key[j0 + j];
    __syncthreads();
    int rr = 0;
#pragma unroll 16
    for (int j = 0; j < 1024; ++j) rr += (tile[j] < my) ? 1 : 0;
    if (rr) atomicAdd(&rankArr[i], rr);
}

__global__ void k_scatter(const int* __restrict__ rankArr, int* __restrict__ order) {
    int i = blockIdx.x * blockDim.x + threadIdx.x;
    if (i >= N) return;
    order[rankArr[i]] = i;   // keys distinct (idx in low bits) -> permutation
}

// ---------------- K3: gather into sorted order --------------------------
__global__ void k_gather(const int* __restrict__ order,
                         const float* __restrict__ box,
                         const int* __restrict__ cls,
                         float4* __restrict__ sbx,
                         float* __restrict__ sarea, int* __restrict__ scls) {
#pragma clang fp contract(off)
    int r = blockIdx.x * blockDim.x + threadIdx.x;
    if (r >= N) return;
    int i = order[r];
    float4 b = ((const float4*)box)[i];          // x, y, w, h
    float hw = b.z * 0.5f, hh = b.w * 0.5f;      // == w/2 exactly
    sbx[r] = make_float4(b.x - hw, b.y - hh, b.x + hw, b.y + hh);
    sarea[r] = b.z * b.w;
    scls[r] = cls[i];
}

// ---------------- K4: suppression bitmask matrix (sorted space) ---------
// block (rowblk=blockIdx.x, colblk=blockIdx.y): 256 rows x 256 cols tile.
// Column data staged in LDS; all lane reads are same-address broadcasts.
__global__ __launch_bounds__(256) void k_matrix(const float4* __restrict__ sbx,
                                                const float* __restrict__ sarea,
                                                const int* __restrict__ scls,
                                                const int* __restrict__ Vcnt,
                                                unsigned long long* __restrict__ mat) {
#pragma clang fp contract(off)
    __shared__ float4 cb[256];
    __shared__ float  ca[256];
    __shared__ int    cc[256];
    int rbase = blockIdx.x * 256;
    int cbase = blockIdx.y * 256;
    if (cbase < rbase) return;               // strictly sub-diagonal: never read
    int V = *Vcnt;
    if (rbase >= V) return;                  // rows >= V never read by scan
    if (cbase >= V) return;                  // word indices >= nc never read

    int r = rbase + threadIdx.x;
    bool active = (r < V);
    float4 rb4; float rar; int rcls;
    if (active) { rb4 = sbx[r]; rar = sarea[r]; rcls = scls[r]; }

    int t = cbase + threadIdx.x;
    cb[threadIdx.x] = sbx[t];
    ca[threadIdx.x] = sarea[t];
    cc[threadIdx.x] = scls[t];
    __syncthreads();
    if (!active) return;

    int rw = r >> 6;
#pragma unroll
    for (int w = 0; w < 4; ++w) {
        int wc = (cbase >> 6) + w;
        if (wc < rw) continue;               // words before row's chunk: never read
        unsigned long long bits = 0ULL;
        int k0 = w * 64;
#pragma unroll 4
        for (int k = 0; k < 64; ++k) {
            int c = cbase + k0 + k;
            float4 c4 = cb[k0 + k];
            // exact float32 op order of the reference:
            float iw = fminf(rb4.z, c4.z) - fmaxf(rb4.x, c4.x);
            iw = fmaxf(iw, 0.0f);
            float ih = fminf(rb4.w, c4.w) - fmaxf(rb4.y, c4.y);
            ih = fmaxf(ih, 0.0f);
            float inter = iw * ih;
            float uni = rar + ca[k0 + k] - inter;
            float iou = __fdiv_rn(inter, uni);       // IEEE-rounded divide
            bool sup = (iou > 0.5f) & (cc[k0 + k] == rcls) & (c > r);
            bits |= ((unsigned long long)sup) << k;
        }
        mat[(size_t)r * NW + wc] = bits;
    }
}

// ---------------- K5: greedy scan, ballot/ctz-skip + eager OR -----------
// Suppression is sparse: sequential steps only at kept ranks with nonzero
// diag word (expected ~0-2 per 64-chunk). Cross-chunk suppression ORed
// eagerly into LDS supp[] right after each chunk's keep word is known
// (coalesced row-contiguous reads; atomicOr fires only on nonzero words).
__global__ void __launch_bounds__(1024) k_scan(const unsigned long long* __restrict__ mat,
                                               const int* __restrict__ Vcnt,
                                               unsigned long long* __restrict__ keepw) {
    __shared__ unsigned long long supp[NW];
    __shared__ unsigned long long diag[64];
    __shared__ unsigned long long kwLDS;
    int tid = threadIdx.x;
    int wv = tid >> 6, lane = tid & 63;
    int V = *Vcnt;
    int nc = (V + 63) >> 6;

    if (tid < NW) { supp[tid] = 0ULL; keepw[tid] = 0ULL; }
    if (tid < 64) {
        diag[tid] = (tid < V && nc > 0) ? mat[(size_t)tid * NW] : 0ULL;
    }
    __syncthreads();

    for (int c = 0; c < nc; ++c) {
        // wave 1: prefetch next chunk's diagonal words (latency hidden
        // behind wave 0's scan; written to LDS after the gather phase)
        unsigned long long pfv = 0ULL;
        if (wv == 1) {
            int r = (c + 1) * 64 + lane;
            if (c + 1 < nc && r < V) pfv = mat[(size_t)r * NW + (c + 1)];
        }
        // wave 0: intra-chunk greedy scan, register/shuffle only
        if (wv == 0) {
            unsigned long long d = diag[lane];
            unsigned long long s = supp[c];
            int lim = V - c * 64;
            unsigned long long limmask = (lim >= 64) ? ~0ULL : ((1ULL << lim) - 1ULL);
            unsigned long long cand = ~s & limmask;   // currently unsuppressed
            unsigned long long nz = __ballot(d != 0ULL);
            unsigned long long todo = cand & nz;      // ranks that need a turn
            while (todo) {
                int k = __builtin_ctzll(todo);        // first kept suppressor
                unsigned long long dk = __shfl(d, k); // its row word (bits > k)
                cand &= ~dk;
                unsigned long long above = (k >= 63) ? 0ULL : ~((2ULL << k) - 1ULL);
                todo = cand & nz & above;
            }
            if (lane == 0) { kwLDS = cand; keepw[c] = cand; }
        }
        __syncthreads();
        // all waves: eager OR of kept rows' future words into supp[]
        int nwf = nc - (c + 1);
        if (nwf > 0) {
            unsigned long long kw = kwLDS;
            int total = 64 * nwf;
            for (int p = tid; p < total; p += 1024) {
                int k = p / nwf;
                int w = c + 1 + (p - k * nwf);        // consecutive tid -> consecutive w
                if ((kw >> k) & 1ULL) {
                    unsigned long long v = mat[(size_t)(c * 64 + k) * NW + w];
                    if (v) atomicOr(&supp[w], v);
                }
            }
        }
        if (wv == 1) diag[lane] = pfv;
        __syncthreads();
    }
}

// ---------------- K6: outputs -------------------------------------------
__global__ void k_out(const float* __restrict__ box,
                      const float* __restrict__ conf,
                      const int* __restrict__ cls,
                      const int* __restrict__ rankArr,
                      const unsigned long long* __restrict__ keepw,
                      float* __restrict__ out) {
    int i = blockIdx.x * blockDim.x + threadIdx.x;
    if (i >= N) return;
    int r = rankArr[i];
    float m = (float)((keepw[r >> 6] >> (r & 63)) & 1ULL);
    float4 b = ((const float4*)box)[i];
    out[i * 5 + 0] = b.x * m;
    out[i * 5 + 1] = b.y * m;
    out[i * 5 + 2] = b.z * m;
    out[i * 5 + 3] = b.w * m;
    out[i * 5 + 4] = conf[i] * m;
    out[5 * N + i] = (float)cls[i];
    out[6 * N + i] = m;
}

// ---------------- launch -------------------------------------------------
extern "C" void kernel_launch(void* const* d_in, const int* in_sizes, int n_in,
                              void* d_out, int out_size, void* d_ws, size_t ws_size,
                              hipStream_t stream) {
    const float* box    = (const float*)d_in[0];
    const float* conf   = (const float*)d_in[1];
    const float* logits = (const float*)d_in[2];
    float* out = (float*)d_out;

    char* ws = (char*)d_ws;
    unsigned long long* key  = (unsigned long long*)(ws + 0);        // 64 KB
    int*    cls     = (int*)   (ws + 65536);                         // 32 KB
    int*    order   = (int*)   (ws + 98304);                         // 32 KB
    int*    rankArr = (int*)   (ws + 131072);                        // 32 KB
    int*    Vcnt    = (int*)   (ws + 163840);                        // 4 B (memset with rankArr)
    unsigned long long* keepw = (unsigned long long*)(ws + 163904);  // 1 KB
    float4* sbx     = (float4*)(ws + 196608);                        // 128 KB
    float*  sarea   = (float*) (ws + 327680);                        // 32 KB
    int*    scls    = (int*)   (ws + 360448);                        // 32 KB
    unsigned long long* mat   = (unsigned long long*)(ws + 458752);  // 8 MB

    hipMemsetAsync(rankArr, 0, N * sizeof(int) + 64, stream);  // rankArr + Vcnt

    k_prep<<<N / 256, 256, 0, stream>>>(box, conf, logits, key, cls, Vcnt);
    k_rank<<<dim3(N / 256, 8), 256, 0, stream>>>(key, rankArr);
    k_scatter<<<N / 256, 256, 0, stream>>>(rankArr, order);
    k_gather<<<N / 256, 256, 0, stream>>>(order, box, cls, sbx, sarea, scls);
    k_matrix<<<dim3(N / 256, N / 256), 256, 0, stream>>>(sbx, sarea, scls, Vcnt, mat);
    k_scan<<<1, 1024, 0, stream>>>(mat, Vcnt, keepw);
    k_out<<<N / 256, 256, 0, stream>>>(box, conf, cls, rankArr, keepw, out);
}

// Round 4
// 129.009 us; speedup vs baseline: 8.0884x; 1.6675x over previous
//
#include <hip/hip_runtime.h>
#include <stdint.h>

#define N 8192
#define NCLS 80
#define NW 128              // N/64 keep-mask words
#define PAIR_CAP (1 << 21)  // 2M pairs (8 MB) -- expected E ~ 2K

// ---------------- K1: per-box prep + workspace zero-init -----------------
__global__ void k_prep(const float* __restrict__ box,
                       const float* __restrict__ conf,
                       const float* __restrict__ logits,
                       unsigned long long* __restrict__ key,
                       int* __restrict__ cls,
                       int* __restrict__ rankArr,
                       int* __restrict__ Vcnt,
                       int* __restrict__ paircnt) {
    int i = blockIdx.x * blockDim.x + threadIdx.x;
    if (i >= N) return;
    rankArr[i] = 0;                       // zero before k_rank's atomics
    if (i == 0) { *Vcnt = 0; *paircnt = 0; }

    float c = conf[i];
    bool valid = c > 0.5f;

    // argmax over 80 logits, first-max wins (matches jnp.argmax)
    const float4* lp = (const float4*)(logits + (size_t)i * NCLS);
    float best = -INFINITY;
    int bi = 0;
#pragma unroll 4
    for (int j4 = 0; j4 < NCLS / 4; ++j4) {
        float4 v = lp[j4];
        if (v.x > best) { best = v.x; bi = j4 * 4 + 0; }
        if (v.y > best) { best = v.y; bi = j4 * 4 + 1; }
        if (v.z > best) { best = v.z; bi = j4 * 4 + 2; }
        if (v.w > best) { best = v.w; bi = j4 * 4 + 3; }
    }
    cls[i] = bi;

    unsigned int kb;
    if (valid) {
        kb = ~__float_as_uint(c);   // ascending kb == descending conf (conf>0)
    } else {
        kb = 0xFFFFFFFFu;           // all invalid sort last, tie-broken by idx
    }
    key[i] = ((unsigned long long)kb << 32) | (unsigned int)i;
}

// ---------------- K2: counting rank (stable argsort), 8-way j-split -----
__global__ __launch_bounds__(256) void k_rank(const unsigned long long* __restrict__ key,
                                              int* __restrict__ rankArr) {
    __shared__ unsigned long long tile[1024];
    int i = blockIdx.x * 256 + threadIdx.x;
    unsigned long long my = key[i];
    int j0 = blockIdx.y * 1024;
    for (int j = threadIdx.x; j < 1024; j += 256) tile[j] = key[j0 + j];
    __syncthreads();
    int rr = 0;
#pragma unroll 16
    for (int j = 0; j < 1024; ++j) rr += (tile[j] < my) ? 1 : 0;
    if (rr) atomicAdd(&rankArr[i], rr);
}

// ---------------- K3: scatter-gather into sorted order + V count --------
__global__ void k_scatgath(const int* __restrict__ rankArr,
                           const unsigned long long* __restrict__ key,
                           const float* __restrict__ box,
                           const int* __restrict__ cls,
                           float4* __restrict__ sbx,
                           float* __restrict__ sarea, int* __restrict__ scls,
                           int* __restrict__ Vcnt) {
#pragma clang fp contract(off)
    int i = blockIdx.x * blockDim.x + threadIdx.x;
    if (i >= N) return;
    int r = rankArr[i];
    float4 b = ((const float4*)box)[i];          // x, y, w, h
    float hw = b.z * 0.5f, hh = b.w * 0.5f;      // == w/2 exactly
    sbx[r] = make_float4(b.x - hw, b.y - hh, b.x + hw, b.y + hh);
    sarea[r] = b.z * b.w;
    scls[r] = cls[i];
    if ((unsigned int)(key[i] >> 32) != 0xFFFFFFFFu) atomicAdd(Vcnt, 1);
}

// ---------------- K4: sparse suppression-pair extraction ----------------
// block (rowblk, colblk): 256 rows x 256 cols; columns staged in LDS
// (same-address broadcast reads). Hits are ~2K/8.4M -> atomic emit.
__global__ __launch_bounds__(256) void k_pairs(const float4* __restrict__ sbx,
                                               const float* __restrict__ sarea,
                                               const int* __restrict__ scls,
                                               const int* __restrict__ Vcnt,
                                               unsigned int* __restrict__ pairs,
                                               int* __restrict__ paircnt) {
#pragma clang fp contract(off)
    __shared__ float4 cb[256];
    __shared__ float  ca[256];
    __shared__ int    cc[256];
    int rbase = blockIdx.x * 256;
    int cbase = blockIdx.y * 256;
    if (cbase < rbase) return;               // strictly sub-diagonal: no c > r
    int V = *Vcnt;
    if (rbase >= V) return;                  // invalid rows never kept
    if (cbase >= V) return;                  // invalid cols never kept

    int r = rbase + threadIdx.x;
    bool active = (r < V);
    float4 rb4; float rar; int rcls;
    if (active) { rb4 = sbx[r]; rar = sarea[r]; rcls = scls[r]; }

    int t = cbase + threadIdx.x;
    cb[threadIdx.x] = sbx[t];
    ca[threadIdx.x] = sarea[t];
    cc[threadIdx.x] = scls[t];
    __syncthreads();
    if (!active) return;

#pragma unroll 4
    for (int k = 0; k < 256; ++k) {
        int c = cbase + k;
        float4 c4 = cb[k];
        // exact float32 op order of the reference:
        float iw = fminf(rb4.z, c4.z) - fmaxf(rb4.x, c4.x);
        iw = fmaxf(iw, 0.0f);
        float ih = fminf(rb4.w, c4.w) - fmaxf(rb4.y, c4.y);
        ih = fmaxf(ih, 0.0f);
        float inter = iw * ih;
        float uni = rar + ca[k] - inter;
        float iou = __fdiv_rn(inter, uni);       // IEEE-rounded divide
        bool sup = (iou > 0.5f) & (cc[k] == rcls) & (c > r) & (c < V);
        if (sup) {
            int idx = atomicAdd(paircnt, 1);
            if (idx < PAIR_CAP) pairs[idx] = ((unsigned int)r << 13) | (unsigned int)c;
        }
    }
}

// ---------------- K5: greedy NMS as sparse Jacobi fixpoint --------------
// keep_{t+1}[c] = valid[c] & !exists edge r->c with keep_t[r].
// Edges go strictly up in rank (DAG) => round t finalizes all ranks of
// dependency-depth <= t; unique fixpoint == sequential greedy scan.
__global__ void __launch_bounds__(256) k_scan(const unsigned int* __restrict__ pairs,
                                              const int* __restrict__ paircnt,
                                              const int* __restrict__ Vcnt,
                                              unsigned long long* __restrict__ keepw) {
    __shared__ unsigned long long keep[NW];
    __shared__ unsigned long long sn[NW];
    __shared__ int chg;
    int tid = threadIdx.x;
    int V = *Vcnt;
    int E = *paircnt; if (E > PAIR_CAP) E = PAIR_CAP;

    int fullw = V >> 6, rem = V & 63;
    unsigned long long vm = 0ULL;
    if (tid < NW) {
        vm = (tid < fullw) ? ~0ULL
           : (tid == fullw && rem) ? ((1ULL << rem) - 1ULL) : 0ULL;
        keep[tid] = vm;                       // K0 = valid
    }
    __syncthreads();

    for (int round = 0; round < 8192; ++round) {
        if (tid < NW) sn[tid] = 0ULL;
        if (tid == 0) chg = 0;
        __syncthreads();
        for (int e = tid; e < E; e += 256) {
            unsigned int p = pairs[e];
            int r = p >> 13, c = p & 8191;
            if ((keep[r >> 6] >> (r & 63)) & 1ULL)
                atomicOr(&sn[c >> 6], 1ULL << (c & 63));
        }
        __syncthreads();
        if (tid < NW) {
            unsigned long long nk = vm & ~sn[tid];
            if (nk != keep[tid]) { keep[tid] = nk; chg = 1; }
        }
        __syncthreads();
        if (!chg) break;                      // uniform (LDS, post-barrier)
    }
    if (tid < NW) keepw[tid] = keep[tid];
}

// ---------------- K6: outputs -------------------------------------------
__global__ void k_out(const float* __restrict__ box,
                      const float* __restrict__ conf,
                      const int* __restrict__ cls,
                      const int* __restrict__ rankArr,
                      const unsigned long long* __restrict__ keepw,
                      float* __restrict__ out) {
    int i = blockIdx.x * blockDim.x + threadIdx.x;
    if (i >= N) return;
    int r = rankArr[i];
    float m = (float)((keepw[r >> 6] >> (r & 63)) & 1ULL);
    float4 b = ((const float4*)box)[i];
    out[i * 5 + 0] = b.x * m;
    out[i * 5 + 1] = b.y * m;
    out[i * 5 + 2] = b.z * m;
    out[i * 5 + 3] = b.w * m;
    out[i * 5 + 4] = conf[i] * m;
    out[5 * N + i] = (float)cls[i];
    out[6 * N + i] = m;
}

// ---------------- launch -------------------------------------------------
extern "C" void kernel_launch(void* const* d_in, const int* in_sizes, int n_in,
                              void* d_out, int out_size, void* d_ws, size_t ws_size,
                              hipStream_t stream) {
    const float* box    = (const float*)d_in[0];
    const float* conf   = (const float*)d_in[1];
    const float* logits = (const float*)d_in[2];
    float* out = (float*)d_out;

    char* ws = (char*)d_ws;
    unsigned long long* key  = (unsigned long long*)(ws + 0);        // 64 KB
    int*    cls     = (int*)   (ws + 65536);                         // 32 KB
    int*    rankArr = (int*)   (ws + 98304);                         // 32 KB
    int*    Vcnt    = (int*)   (ws + 131072);                        // 4 B
    int*    paircnt = (int*)   (ws + 131136);                        // 4 B
    unsigned long long* keepw = (unsigned long long*)(ws + 131200);  // 1 KB
    float4* sbx     = (float4*)(ws + 163840);                        // 128 KB
    float*  sarea   = (float*) (ws + 294912);                        // 32 KB
    int*    scls    = (int*)   (ws + 327680);                        // 32 KB
    unsigned int* pairs = (unsigned int*)(ws + 393216);              // 8 MB

    k_prep<<<N / 256, 256, 0, stream>>>(box, conf, logits, key, cls,
                                        rankArr, Vcnt, paircnt);
    k_rank<<<dim3(N / 256, 8), 256, 0, stream>>>(key, rankArr);
    k_scatgath<<<N / 256, 256, 0, stream>>>(rankArr, key, box, cls,
                                            sbx, sarea, scls, Vcnt);
    k_pairs<<<dim3(N / 256, N / 256), 256, 0, stream>>>(sbx, sarea, scls, Vcnt,
                                                        pairs, paircnt);
    k_scan<<<1, 256, 0, stream>>>(pairs, paircnt, Vcnt, keepw);
    k_out<<<N / 256, 256, 0, stream>>>(box, conf, cls, rankArr, keepw, out);
}